// Round 11
// baseline (318.117 us; speedup 1.0000x reference)
//
#include <hip/hip_runtime.h>
#include <hip/hip_bf16.h>

// LocalBlock: tpose+LN1 -> qkv GEMM -> multi-dilate attn(+xn) -> proj GEMM(+x, bf16 y)
//            -> fused {LN2 + fc1 + gelu + fc2 + resid + transposed f32 out}
// gemmW (qkv/proj): round-8 structure: BM=128 BN=192 BK=32, 8 waves, ring-4 80KB,
//   counted vmcnt, 1 barrier/iter, LDS-coalesced epilogues.
// mlp_fused: 64-row blocks, 1024 thr, h kept in LDS (kills 152MB hbuf traffic).

#define B_   8
#define C_   384
#define W_   56
#define HW_  3136
#define N_   25088
#define HID_ 1536
#define C3_  1152

typedef __attribute__((ext_vector_type(8))) short short8v;
typedef __attribute__((ext_vector_type(4))) float f32x4;
typedef __attribute__((ext_vector_type(4))) unsigned short ushort4v;

__device__ __forceinline__ float bf2f(unsigned short u) {
  union { float f; unsigned u; } c; c.u = ((unsigned)u) << 16; return c.f;
}
__device__ __forceinline__ unsigned short f2bf(float f) {
  unsigned u = __float_as_uint(f);
  u = (u + 0x7FFFu + ((u >> 16) & 1u)) >> 16;
  return (unsigned short)u;
}
__device__ __forceinline__ float gelu_fast(float x) {
  const float z = 1.5957691216057308f * (x + 0.044715f * x * x * x);
  return x / (1.f + __expf(-z));
}

#define GLL(gsrc, ldst) __builtin_amdgcn_global_load_lds( \
    (const __attribute__((address_space(1))) void*)(gsrc), \
    (__attribute__((address_space(3))) void*)(ldst), 16, 0, 0)

// ---------------- weight fp32 -> bf16 (plain [n][k]) ----------------
__global__ void cvt_weights(const float* __restrict__ qw, const float* __restrict__ pw,
                            const float* __restrict__ f1, const float* __restrict__ f2,
                            unsigned short* __restrict__ o) {
  int i = blockIdx.x * 256 + threadIdx.x;
  if (i < 442368)        o[i] = f2bf(qw[i]);
  else if (i < 589824)   o[i] = f2bf(pw[i - 442368]);
  else if (i < 1179648)  o[i] = f2bf(f1[i - 589824]);
  else if (i < 1769472)  o[i] = f2bf(f2[i - 1179648]);
}

// ---------------- fused transpose + LN1: x[B,C,HW] -> xpb[N,C] bf16, xn[N,C] bf16 ---------
__global__ __launch_bounds__(256)
void tpose_ln(const float* __restrict__ x, unsigned short* __restrict__ xpb,
              unsigned short* __restrict__ xnb,
              const float* __restrict__ gam, const float* __restrict__ bet) {
  __shared__ float ft[64][385];
  __shared__ float mstat[64], rstat[64];
  const int tid = threadIdx.x;
  const int nb0 = blockIdx.x * 64;
  const int bb = nb0 / HW_, hw0 = nb0 - bb * HW_;
  const float* xb = x + (size_t)bb * C_ * HW_ + hw0;
#pragma unroll
  for (int p = 0; p < 24; ++p) {
    const int c = p * 16 + (tid >> 4);
    f32x4 v = *(const f32x4*)&xb[(size_t)c * HW_ + (tid & 15) * 4];
#pragma unroll
    for (int j = 0; j < 4; ++j) ft[(tid & 15) * 4 + j][c] = v[j];
  }
  __syncthreads();
  const int l16 = tid & 15, g16 = tid >> 4;
#pragma unroll
  for (int rr = 0; rr < 4; ++rr) {
    const int row = g16 * 4 + rr;
    float s = 0.f, ss = 0.f;
#pragma unroll
    for (int k2 = 0; k2 < 24; ++k2) { float v = ft[row][l16 + k2 * 16]; s += v; ss += v * v; }
    s += __shfl_xor(s, 8); ss += __shfl_xor(ss, 8);
    s += __shfl_xor(s, 4); ss += __shfl_xor(ss, 4);
    s += __shfl_xor(s, 2); ss += __shfl_xor(ss, 2);
    s += __shfl_xor(s, 1); ss += __shfl_xor(ss, 1);
    if (l16 == 0) {
      const float mean = s * (1.f / 384.f);
      const float var = ss * (1.f / 384.f) - mean * mean;
      mstat[row] = mean; rstat[row] = rsqrtf(var + 1e-5f);
    }
  }
  __syncthreads();
  const int row = tid >> 2, part = tid & 3;
  const float mean = mstat[row], rstd = rstat[row];
  unsigned short* xpr = xpb + (size_t)(nb0 + row) * C_ + part * 96;
  unsigned short* xr = xnb + (size_t)(nb0 + row) * C_ + part * 96;
#pragma unroll
  for (int q = 0; q < 12; ++q) {
    short8v oraw, oln;
#pragma unroll
    for (int e = 0; e < 8; ++e) {
      const int c = part * 96 + q * 8 + e;
      const float v = ft[row][c];
      oraw[e] = (short)f2bf(v);
      oln[e] = (short)f2bf((v - mean) * rstd * gam[c] + bet[c]);
    }
    *(short8v*)&xpr[q * 8] = oraw;
    *(short8v*)&xr[q * 8] = oln;
  }
}

// ---------------- GEMM (round-8 structure): out[M,NOUT] = A[M,K] @ W[NOUT,K]^T -----------
// MODE 0: bf16 out (qkv, no bias)   MODE 1: bf16 out = resid + v + bias (proj)
template <int MODE, int NOUT, int K>
__global__ __launch_bounds__(512, 4)
void gemmW(const unsigned short* __restrict__ A, const unsigned short* __restrict__ Wt,
           const float* __restrict__ bias, const unsigned short* __restrict__ resid,
           void* __restrict__ outp) {
  constexpr int KT = K / 32;
  constexpr int SLOTU = 320 * 32;            // 20 KB per slot
  __shared__ unsigned short sm[4 * SLOTU];   // 80 KiB ring-4
  const int tid = threadIdx.x, l = tid & 63, wv = tid >> 6;
  const int wm = wv >> 2, wn = wv & 3;

  const int nx = gridDim.x;
  const int nwg = nx * gridDim.y;
  const int bid = blockIdx.y * nx + blockIdx.x;
  const int wg = (bid & 7) * (nwg >> 3) + (bid >> 3);
  const int m0 = (wg / nx) * 128, n0 = (wg % nx) * 192;

  const int cpw = (wv >= 4) ? 2 : 3;
  const int cg = (((l & 3) ^ ((l >> 3) & 3)) << 3);
  const unsigned short* gp[3]; int gd[3];
#pragma unroll
  for (int i = 0; i < 3; ++i) {
    const int ci = wv + 8 * i;
    const int rl = (ci < 20 ? ci : 0) * 16 + (l >> 2);
    gp[i] = (ci < 8) ? A + (size_t)(m0 + rl) * K + cg
                     : Wt + (size_t)(n0 + (rl - 128)) * K + cg;
    gd[i] = (ci < 20 ? ci : 0) * 512 + l * 8;
  }
  auto stage = [&](int t) {
    const int sb = (t & 3) * SLOTU;
    for (int i = 0; i < cpw; ++i) GLL(gp[i] + t * 32, &sm[sb + gd[i]]);
  };

  const int fr = l & 15, g = l >> 4, g4 = g * 4;
  const int sfr = (fr * 4 + (g ^ ((fr >> 1) & 3))) * 8;
  int aoff[4], boff[3];
#pragma unroll
  for (int mt = 0; mt < 4; ++mt) aoff[mt] = (wm * 4 + mt) * 512 + sfr;
#pragma unroll
  for (int nt = 0; nt < 3; ++nt) boff[nt] = (8 + wn * 3 + nt) * 512 + sfr;

  f32x4 acc[4][3] = {};

  stage(0); stage(1); stage(2);
  for (int t = 0; t < KT; ++t) {
    const int rem = KT - t;
    if (rem > 2) {
      if (cpw == 3) asm volatile("s_waitcnt vmcnt(6)" ::: "memory");
      else          asm volatile("s_waitcnt vmcnt(4)" ::: "memory");
    } else if (rem == 2) {
      if (cpw == 3) asm volatile("s_waitcnt vmcnt(3)" ::: "memory");
      else          asm volatile("s_waitcnt vmcnt(2)" ::: "memory");
    } else {
      asm volatile("s_waitcnt vmcnt(0)" ::: "memory");
    }
    __builtin_amdgcn_sched_barrier(0);
    __builtin_amdgcn_s_barrier();
    __builtin_amdgcn_sched_barrier(0);
    if (t + 3 < KT) stage(t + 3);
    __builtin_amdgcn_sched_barrier(0);
    const int sb = (t & 3) * SLOTU;
    short8v av[4], bv[3];
#pragma unroll
    for (int mt = 0; mt < 4; ++mt) av[mt] = *(const short8v*)&sm[sb + aoff[mt]];
#pragma unroll
    for (int nt = 0; nt < 3; ++nt) bv[nt] = *(const short8v*)&sm[sb + boff[nt]];
    __builtin_amdgcn_s_setprio(1);
#pragma unroll
    for (int mt = 0; mt < 4; ++mt)
#pragma unroll
      for (int nt = 0; nt < 3; ++nt)
        acc[mt][nt] = __builtin_amdgcn_mfma_f32_16x16x32_bf16(bv[nt], av[mt], acc[mt][nt], 0, 0, 0);
    __builtin_amdgcn_s_setprio(0);
    __builtin_amdgcn_sched_barrier(0);
  }

  // SWAP epilogue: m = wm*64+mt*16+fr ; n = wn*48+nt*16+g4+j -> LDS [128][200] -> coalesced
  __syncthreads();
#pragma unroll
  for (int mt = 0; mt < 4; ++mt) {
    const int ml = wm * 64 + mt * 16 + fr;
#pragma unroll
    for (int nt = 0; nt < 3; ++nt) {
      const int nl = wn * 48 + nt * 16 + g4;
      f32x4 v = acc[mt][nt];
      ushort4v pk;
#pragma unroll
      for (int j = 0; j < 4; ++j) pk[j] = f2bf(v[j]);
      *(ushort4v*)&sm[ml * 200 + nl] = pk;
    }
  }
  __syncthreads();
  unsigned short* op = (unsigned short*)outp;
#pragma unroll
  for (int it = 0; it < 6; ++it) {
    const int slot = it * 512 + tid;
    const int row = slot / 24, grp = slot - row * 24;
    const int n = n0 + grp * 8;
    short8v v = *(const short8v*)&sm[row * 200 + grp * 8];
    if constexpr (MODE == 1) {
      const f32x4 b0 = *(const f32x4*)&bias[n];
      const f32x4 b1 = *(const f32x4*)&bias[n + 4];
      const short8v r8 = *(const short8v*)&resid[(size_t)(m0 + row) * C_ + n];
#pragma unroll
      for (int e = 0; e < 8; ++e)
        v[e] = (short)f2bf(bf2f((unsigned short)v[e]) + (e < 4 ? b0[e] : b1[e - 4])
                           + bf2f((unsigned short)r8[e]));
    }
    *(short8v*)&op[(size_t)(m0 + row) * NOUT + n] = v;
  }
}

// ---------------- fused MLP: y -> LN2 -> fc1+gelu -> fc2 -> +y -> d_out[B,C,HW] f32 ------
// block = 64 rows, 1024 thr (16 waves). LDS: xn2[64][400] | h[64][200] | W-ring 3x24KB.
__global__ __launch_bounds__(1024, 4)
void mlp_fused(const unsigned short* __restrict__ y,
               const unsigned short* __restrict__ W1, const float* __restrict__ fb1,
               const unsigned short* __restrict__ W2, const float* __restrict__ fb2,
               const float* __restrict__ gam, const float* __restrict__ bet,
               float* __restrict__ out) {
  __shared__ unsigned short sm[75264];   // 147 KiB
  constexpr int HB = 25600, RB = 38400, SLOT = 12288;
  const int tid = threadIdx.x, l = tid & 63, wv = tid >> 6;
  const int fr = l & 15, g = l >> 4, g4 = g << 2;
  const int bid = blockIdx.x;
  const int wg = (bid & 7) * 49 + (bid >> 3);   // 392 = 8*49, bijective XCD swizzle
  const int m0 = wg * 64;
  const int cg = (((l & 3) ^ ((l >> 3) & 3)) << 3);
  const int sfr = (fr * 4 + (g ^ ((fr >> 1) & 3))) * 8;
  const int wvm1 = wv >> 2, wvn1 = wv & 3;
  const int wvm2 = wv >> 3, wvn2 = wv & 7;

  // ---- stage y tile [64][384] into ring area ----
#pragma unroll
  for (int r = 0; r < 3; ++r) {
    const int idx = r * 1024 + tid;
    GLL(y + (size_t)(m0 + idx / 48) * C_ + (idx % 48) * 8, &sm[RB + idx * 8]);
  }
  asm volatile("s_waitcnt vmcnt(0)" ::: "memory");
  __syncthreads();

  // ---- LN2 -> xn2 (padded [64][400], conflict-free A-frag reads) ----
#pragma unroll
  for (int rr = 0; rr < 4; ++rr) {
    const int row = wv * 4 + rr;
    float v[8]; float s = 0.f, ss = 0.f;
    if (l < 48) {
      short8v rv = *(const short8v*)&sm[RB + row * 384 + l * 8];
#pragma unroll
      for (int e = 0; e < 8; ++e) { v[e] = bf2f((unsigned short)rv[e]); s += v[e]; ss += v[e] * v[e]; }
    } else {
#pragma unroll
      for (int e = 0; e < 8; ++e) v[e] = 0.f;
    }
#pragma unroll
    for (int off = 32; off; off >>= 1) { s += __shfl_xor(s, off); ss += __shfl_xor(ss, off); }
    const float mean = s * (1.f / 384.f);
    const float rstd = rsqrtf(ss * (1.f / 384.f) - mean * mean + 1e-5f);
    if (l < 48) {
      const f32x4 ga = *(const f32x4*)&gam[l * 8];
      const f32x4 gb = *(const f32x4*)&gam[l * 8 + 4];
      const f32x4 ba = *(const f32x4*)&bet[l * 8];
      const f32x4 bb2 = *(const f32x4*)&bet[l * 8 + 4];
      short8v o;
#pragma unroll
      for (int e = 0; e < 8; ++e)
        o[e] = (short)f2bf((v[e] - mean) * rstd * (e < 4 ? ga[e] : gb[e - 4])
                           + (e < 4 ? ba[e] : bb2[e - 4]));
      *(short8v*)&sm[row * 400 + l * 8] = o;
    }
  }
  __syncthreads();

  f32x4 acc2[2][3] = {};

  for (int nc = 0; nc < 8; ++nc) {
    // ===== GEMM1: h[64][192] = xn2 @ W1[nc*192..]^T  (K=384, 12 steps, ring-3) =====
    f32x4 acc1[3] = {};
    const unsigned short* w1p = W1 + (size_t)(nc * 192 + wv * 16 + (l >> 2)) * C_ + cg;
    const int d1 = wv * 512 + l * 8;
    if (wv < 12) { GLL(w1p, &sm[RB + d1]); GLL(w1p + 32, &sm[RB + SLOT + d1]); }
    for (int t = 0; t < 12; ++t) {
      if (t < 11) asm volatile("s_waitcnt vmcnt(1)" ::: "memory");
      else        asm volatile("s_waitcnt vmcnt(0)" ::: "memory");
      __builtin_amdgcn_sched_barrier(0);
      __builtin_amdgcn_s_barrier();
      __builtin_amdgcn_sched_barrier(0);
      if (wv < 12 && t + 2 < 12) GLL(w1p + (t + 2) * 32, &sm[RB + ((t + 2) % 3) * SLOT + d1]);
      const int sb = RB + (t % 3) * SLOT;
      short8v av = *(const short8v*)&sm[(wvm1 * 16 + fr) * 400 + ((t * 4 + g) << 3)];
      short8v bv[3];
#pragma unroll
      for (int nt = 0; nt < 3; ++nt) bv[nt] = *(const short8v*)&sm[sb + (wvn1 * 3 + nt) * 512 + sfr];
      __builtin_amdgcn_s_setprio(1);
#pragma unroll
      for (int nt = 0; nt < 3; ++nt)
        acc1[nt] = __builtin_amdgcn_mfma_f32_16x16x32_bf16(bv[nt], av, acc1[nt], 0, 0, 0);
      __builtin_amdgcn_s_setprio(0);
      __builtin_amdgcn_sched_barrier(0);
    }
    // gelu + bias -> h (padded [64][200]); lane: m = wvm1*16+fr, n = wvn1*48+nt*16+g4+j
#pragma unroll
    for (int nt = 0; nt < 3; ++nt) {
      const int n = wvn1 * 48 + nt * 16 + g4;
      const f32x4 bi = *(const f32x4*)&fb1[nc * 192 + n];
      ushort4v pk;
#pragma unroll
      for (int j = 0; j < 4; ++j) pk[j] = f2bf(gelu_fast(acc1[nt][j] + bi[j]));
      *(ushort4v*)&sm[HB + (wvm1 * 16 + fr) * 200 + n] = pk;
    }
    __syncthreads();

    // ===== GEMM2: acc2 += h @ W2[:, nc*192..]^T  (k2=192, 6 steps, ring-3) =====
    const unsigned short* w2p = W2 + (size_t)(wv * 16 + (l >> 2)) * HID_ + nc * 192 + cg;
    const unsigned short* w2q = W2 + (size_t)((wv + 16) * 16 + (l >> 2)) * HID_ + nc * 192 + cg;
    const int d2 = wv * 512 + l * 8, d2b = (wv + 16) * 512 + l * 8;
    GLL(w2p, &sm[RB + d2]);
    if (wv < 8) GLL(w2q, &sm[RB + d2b]);
    GLL(w2p + 32, &sm[RB + SLOT + d2]);
    if (wv < 8) GLL(w2q + 32, &sm[RB + SLOT + d2b]);
    for (int t = 0; t < 6; ++t) {
      if (t < 5) {
        if (wv < 8) asm volatile("s_waitcnt vmcnt(2)" ::: "memory");
        else        asm volatile("s_waitcnt vmcnt(1)" ::: "memory");
      } else {
        asm volatile("s_waitcnt vmcnt(0)" ::: "memory");
      }
      __builtin_amdgcn_sched_barrier(0);
      __builtin_amdgcn_s_barrier();
      __builtin_amdgcn_sched_barrier(0);
      if (t + 2 < 6) {
        GLL(w2p + (t + 2) * 32, &sm[RB + ((t + 2) % 3) * SLOT + d2]);
        if (wv < 8) GLL(w2q + (t + 2) * 32, &sm[RB + ((t + 2) % 3) * SLOT + d2b]);
      }
      const int sb = RB + (t % 3) * SLOT;
      short8v av2[2], bv2[3];
#pragma unroll
      for (int mt = 0; mt < 2; ++mt)
        av2[mt] = *(const short8v*)&sm[HB + (wvm2 * 32 + mt * 16 + fr) * 200 + ((t * 4 + g) << 3)];
#pragma unroll
      for (int nt = 0; nt < 3; ++nt) bv2[nt] = *(const short8v*)&sm[sb + (wvn2 * 3 + nt) * 512 + sfr];
      __builtin_amdgcn_s_setprio(1);
#pragma unroll
      for (int mt = 0; mt < 2; ++mt)
#pragma unroll
        for (int nt = 0; nt < 3; ++nt)
          acc2[mt][nt] = __builtin_amdgcn_mfma_f32_16x16x32_bf16(av2[mt], bv2[nt], acc2[mt][nt], 0, 0, 0);
      __builtin_amdgcn_s_setprio(0);
      __builtin_amdgcn_sched_barrier(0);
    }
    __syncthreads();
  }

  // ===== epilogue: out[B,C,HW] = acc2 + b2 + y, via LDS transpose, coalesced f32x4 =====
  // lane: m = m0 + wvm2*32 + mt*16 + g4 + j ; c = wvn2*48 + nt*16 + fr
  float* lf = (float*)sm;   // 96 cols x 16 row-quads f32x4 = 24 KB (xn2 region, dead)
#pragma unroll
  for (int q = 0; q < 4; ++q) {
    if ((wvn2 >> 1) == q) {
#pragma unroll
      for (int mt = 0; mt < 2; ++mt) {
#pragma unroll
        for (int nt = 0; nt < 3; ++nt) {
          const int cl = (wvn2 & 1) * 48 + nt * 16 + fr;   // 0..95
          const int u = wvm2 * 8 + mt * 4 + g;             // 0..15
          *(f32x4*)&lf[cl * 64 + (((u & 8) | ((u & 7) ^ (cl & 7))) << 2)] = acc2[mt][nt];
        }
      }
    }
    __syncthreads();
#pragma unroll
    for (int it = 0; it < 2; ++it) {
      const int slot = it * 1024 + tid;
      if (slot < 1536) {
        const int cl = slot >> 4, u = slot & 15;
        f32x4 v = *(const f32x4*)&lf[cl * 64 + (((u & 8) | ((u & 7) ^ (cl & 7))) << 2)];
        const int cgl = q * 96 + cl;
        const int mg = m0 + u * 4;
        const float bo = fb2[cgl];
#pragma unroll
        for (int j = 0; j < 4; ++j)
          v[j] += bo + bf2f(y[(size_t)(mg + j) * C_ + cgl]);
        const int bb = mg / HW_, hw = mg - bb * HW_;
        *(f32x4*)&out[((size_t)bb * C_ + cgl) * HW_ + hw] = v;
      }
    }
    __syncthreads();
  }
}

// ---------------- multi-dilate local attention (+xn) ----------------
__global__ __launch_bounds__(256)
void attn_kernel(const unsigned short* __restrict__ qkv,
                 const unsigned short* __restrict__ xn,
                 unsigned short* __restrict__ aout) {
  const int gid = blockIdx.x * 256 + threadIdx.x;
  const int n = gid / 12;
  const int r = gid - n * 12;
  const int dil = (r >> 2) + 1;
  const int b = n / HW_;
  const int hw = n - b * HW_;
  const int h = hw / W_;
  const int w = hw - h * W_;

  const size_t base = (size_t)n * C3_ + (size_t)r * 32;
  float q[32];
  {
    const short8v* vp = (const short8v*)(qkv + base);
#pragma unroll
    for (int c8 = 0; c8 < 4; ++c8) {
      short8v v = vp[c8];
#pragma unroll
      for (int e = 0; e < 8; ++e) q[c8 * 8 + e] = bf2f((unsigned short)v[e]);
    }
  }

  float logit[9];
#pragma unroll
  for (int ti = 0; ti < 3; ++ti)
#pragma unroll
    for (int tj = 0; tj < 3; ++tj) {
      const int t = ti * 3 + tj;
      const int hn = h + (ti - 1) * dil, wn = w + (tj - 1) * dil;
      if ((unsigned)hn < 56u && (unsigned)wn < 56u) {
        const int nb = n + (ti - 1) * dil * W_ + (tj - 1) * dil;
        const short8v* kp = (const short8v*)(qkv + (size_t)nb * C3_ + C_ + (size_t)r * 32);
        float dot = 0.f;
#pragma unroll
        for (int c8 = 0; c8 < 4; ++c8) {
          short8v v = kp[c8];
#pragma unroll
          for (int e = 0; e < 8; ++e) dot += q[c8 * 8 + e] * bf2f((unsigned short)v[e]);
        }
        logit[t] = dot * 0.17677669529663688f;
      } else {
        logit[t] = 0.f;  // zero-padded taps participate with logit 0
      }
    }

  float mx = logit[0];
#pragma unroll
  for (int t = 1; t < 9; ++t) mx = fmaxf(mx, logit[t]);
  float wgt[9]; float se = 0.f;
#pragma unroll
  for (int t = 0; t < 9; ++t) { wgt[t] = __expf(logit[t] - mx); se += wgt[t]; }
  const float inv = 1.f / se;

  float acc[32];
#pragma unroll
  for (int c = 0; c < 32; ++c) acc[c] = 0.f;
#pragma unroll
  for (int ti = 0; ti < 3; ++ti)
#pragma unroll
    for (int tj = 0; tj < 3; ++tj) {
      const int t = ti * 3 + tj;
      const int hn = h + (ti - 1) * dil, wn = w + (tj - 1) * dil;
      if ((unsigned)hn < 56u && (unsigned)wn < 56u) {
        const int nb = n + (ti - 1) * dil * W_ + (tj - 1) * dil;
        const short8v* vp = (const short8v*)(qkv + (size_t)nb * C3_ + 2 * C_ + (size_t)r * 32);
        const float wt = wgt[t];
#pragma unroll
        for (int c8 = 0; c8 < 4; ++c8) {
          short8v v = vp[c8];
#pragma unroll
          for (int e = 0; e < 8; ++e) acc[c8 * 8 + e] += wt * bf2f((unsigned short)v[e]);
        }
      }
    }

  const size_t obase = (size_t)n * C_ + (size_t)r * 32;
  const short8v* xv = (const short8v*)(xn + obase);
  short8v ov[4];
#pragma unroll
  for (int c8 = 0; c8 < 4; ++c8) {
    short8v v = xv[c8];
#pragma unroll
    for (int e = 0; e < 8; ++e)
      ov[c8][e] = (short)f2bf(acc[c8 * 8 + e] * inv + bf2f((unsigned short)v[e]));
  }
  short8v* op = (short8v*)(aout + obase);
#pragma unroll
  for (int c8 = 0; c8 < 4; ++c8) op[c8] = ov[c8];
}

extern "C" void kernel_launch(void* const* d_in, const int* in_sizes, int n_in,
                              void* d_out, int out_size, void* d_ws, size_t ws_size,
                              hipStream_t stream) {
  const float* x = (const float*)d_in[0];
  const float* qkv_w = (const float*)d_in[1];
  const float* proj_w = (const float*)d_in[2];
  const float* proj_b = (const float*)d_in[3];
  const float* n1_g = (const float*)d_in[4];
  const float* n1_b = (const float*)d_in[5];
  const float* n2_g = (const float*)d_in[6];
  const float* n2_b = (const float*)d_in[7];
  const float* fc1_w = (const float*)d_in[8];
  const float* fc1_b = (const float*)d_in[9];
  const float* fc2_w = (const float*)d_in[10];
  const float* fc2_b = (const float*)d_in[11];

  char* ws = (char*)d_ws;
  unsigned short* xpb = (unsigned short*)ws;                     // [N,C] bf16 (x transposed)
  unsigned short* xn = (unsigned short*)(ws + 19267584);         // [N,C] bf16 (LN1 out)
  unsigned short* qkvb = (unsigned short*)(ws + 38535168);       // [N,1152] bf16
  unsigned short* abuf = (unsigned short*)(ws + 96337920);       // [N,C] bf16
  unsigned short* y = (unsigned short*)(ws + 115605504);         // [N,C] bf16 residual stream
  unsigned short* wq = (unsigned short*)(ws + 134873088);        // weights bf16 [n][k]
  unsigned short* wp = wq + 442368;
  unsigned short* wf1 = wp + 147456;
  unsigned short* wf2 = wf1 + 589824;

  cvt_weights<<<6912, 256, 0, stream>>>(qkv_w, proj_w, fc1_w, fc2_w, wq);
  tpose_ln<<<392, 256, 0, stream>>>(x, xpb, xn, n1_g, n1_b);
  gemmW<0, C3_, C_><<<dim3(6, 196), 512, 0, stream>>>(xn, wq, nullptr, nullptr, qkvb);
  attn_kernel<<<1176, 256, 0, stream>>>(qkvb, xn, abuf);
  gemmW<1, C_, C_><<<dim3(2, 196), 512, 0, stream>>>(abuf, wp, proj_b, xpb, y);
  mlp_fused<<<392, 1024, 0, stream>>>(y, wf1, fc1_b, wf2, fc2_b, n2_g, n2_b, (float*)d_out);
}